// Round 1
// baseline (706.184 us; speedup 1.0000x reference)
//
#include <hip/hip_runtime.h>
#include <math.h>

#define TT 65536
#define DD 256
#define EE 8
#define HH 512
#define OO 256

typedef unsigned int u32;
typedef unsigned short u16;
typedef __attribute__((ext_vector_type(4))) float f32x4;
typedef __attribute__((ext_vector_type(2))) u32 u32x2;
typedef __attribute__((ext_vector_type(4))) u32 u32x4;
typedef __attribute__((ext_vector_type(8))) __bf16 bf16x8;

__device__ __forceinline__ u16 f2bf(float f) {
    u32 u = __builtin_bit_cast(u32, f);
    u32 r = (u + 0x7fffu + ((u >> 16) & 1u)) >> 16;
    return (u16)r;
}

__device__ __forceinline__ bf16x8 ld_frag(const void* p) {
    u32x4 v = *(const u32x4*)p;
    return __builtin_bit_cast(bf16x8, v);
}

// ---------------- convert/transpose weights ----------------
// w1 [E][D][H] f32 -> w1t [E][H][D] bf16
__global__ __launch_bounds__(256) void k_conv_w1(const float* __restrict__ w1, u16* __restrict__ w1t) {
    int i = blockIdx.x * 256 + threadIdx.x;            // < E*H*D = 1M
    int d = i & 255, h = (i >> 8) & 511, e = i >> 17;
    w1t[i] = f2bf(w1[((size_t)e << 17) + ((size_t)d << 9) + h]);
}
// w2 [E][H][O] f32 -> w2t [E][O][H] bf16
__global__ __launch_bounds__(256) void k_conv_w2(const float* __restrict__ w2, u16* __restrict__ w2t) {
    int i = blockIdx.x * 256 + threadIdx.x;            // < E*O*H = 1M
    int h = i & 511, o = (i >> 9) & 255, e = i >> 17;
    w2t[i] = f2bf(w2[((size_t)e << 17) + ((size_t)h << 8) + o]);
}

// ---------------- gating: softmax, entropy, top-p mask, weights ----------------
__global__ __launch_bounds__(256) void k_gating(const float* __restrict__ x,
                                                const float* __restrict__ gw,
                                                const float* __restrict__ gb,
                                                float* __restrict__ wt,
                                                double* __restrict__ part) {
    __shared__ float gws[DD * EE];
    __shared__ float gbs[EE];
    __shared__ double red[256];
    int tid = threadIdx.x;
    for (int i = tid; i < DD * EE; i += 256) gws[i] = gw[i];
    if (tid < EE) gbs[tid] = gb[tid];
    __syncthreads();

    int t = blockIdx.x * 256 + tid;
    double l[EE];
#pragma unroll
    for (int e = 0; e < EE; ++e) l[e] = (double)gbs[e];

    const f32x4* xr = (const f32x4*)(x + (size_t)t * DD);
    for (int d4 = 0; d4 < DD / 4; ++d4) {
        f32x4 xv = xr[d4];
#pragma unroll
        for (int j = 0; j < 4; ++j) {
            double xs = (double)xv[j];
            int d = d4 * 4 + j;
#pragma unroll
            for (int e = 0; e < EE; ++e) l[e] += xs * (double)gws[d * EE + e];
        }
    }
    double mx = l[0];
#pragma unroll
    for (int e = 1; e < EE; ++e) mx = l[e] > mx ? l[e] : mx;
    double p[EE], s = 0.0;
#pragma unroll
    for (int e = 0; e < EE; ++e) { p[e] = exp(l[e] - mx); s += p[e]; }
    double inv = 1.0 / s;
    double ent = 0.0;
#pragma unroll
    for (int e = 0; e < EE; ++e) { p[e] *= inv; ent += p[e] * log(p[e] + 1e-8); }

    // top-p mask (stable descending argsort semantics, no dynamic indexing)
    bool mask[EE];
#pragma unroll
    for (int e = 0; e < EE; ++e) {
        double c = 0.0; int rk = 0;
#pragma unroll
        for (int f = 0; f < EE; ++f) {
            bool before = (p[f] > p[e]) || (p[f] == p[e] && f < e);
            if (before) { c += p[f]; rk++; }
        }
        c += p[e];                       // inclusive cumsum at e's sorted position
        mask[e] = (c <= 0.7) || (rk == 0);
    }
    double ms = 0.0;
#pragma unroll
    for (int e = 0; e < EE; ++e) if (mask[e]) ms += p[e];
    double inv2 = 1.0 / ms;
#pragma unroll
    for (int e = 0; e < EE; ++e) wt[(size_t)t * EE + e] = (float)(mask[e] ? p[e] * inv2 : 0.0);

    red[tid] = -ent;
    __syncthreads();
    for (int st = 128; st > 0; st >>= 1) {
        if (tid < st) red[tid] += red[tid + st];
        __syncthreads();
    }
    if (tid == 0) part[blockIdx.x] = red[0];
}

__global__ __launch_bounds__(256) void k_final(const double* __restrict__ part, float* __restrict__ loss) {
    __shared__ double red[256];
    int tid = threadIdx.x;
    red[tid] = part[tid];
    __syncthreads();
    for (int st = 128; st > 0; st >>= 1) {
        if (tid < st) red[tid] += red[tid + st];
        __syncthreads();
    }
    if (tid == 0) loss[0] = (float)(red[0] / (double)TT);
}

// ---------------- fused MoE MLP ----------------
// 64 tokens/block, 4 waves. Per expert, per 256-wide H-chunk:
//   GEMM1: Hf[h][tok] = X @ W1 (computed transposed), gelu, *weight -> Hs (bf16, swizzled LDS)
//   GEMM2: oacc[tok][o] += Hs @ W2
__global__ __launch_bounds__(256, 2) void k_moe(const float* __restrict__ x,
                                                const u16* __restrict__ w1t,
                                                const u16* __restrict__ w2t,
                                                const float* __restrict__ b1,
                                                const float* __restrict__ b2,
                                                const float* __restrict__ wt,
                                                float* __restrict__ out) {
    __shared__ __align__(16) unsigned char smem[75776];
    unsigned char* Xs = smem;                     // 64 x 256 bf16 (swizzled) = 32768
    unsigned char* Hs = smem + 32768;             // 64 x 256 bf16 (swizzled) = 32768
    float* wts = (float*)(smem + 65536);          // 64 x 8 f32 = 2048
    float* b2s = (float*)(smem + 67584);          // 8 x 256 f32 = 8192

    const int tid = threadIdx.x;
    const int wid = tid >> 6;
    const int lane = tid & 63;
    const int lr = lane & 15;
    const int lg = lane >> 4;
    const int t0 = blockIdx.x * 64;

    // stage X tile: f32 -> bf16, XOR-swizzled rows (row stride 512B)
    {
        const f32x4* xsrc = (const f32x4*)(x + (size_t)t0 * DD);
#pragma unroll
        for (int i = 0; i < 8; ++i) {
            int L = i * 4096 + tid * 16;          // byte offset in bf16 tile
            f32x4 a = xsrc[L >> 3];
            f32x4 b = xsrc[(L >> 3) + 1];
            u32x4 o;
            o.x = (u32)f2bf(a[0]) | ((u32)f2bf(a[1]) << 16);
            o.y = (u32)f2bf(a[2]) | ((u32)f2bf(a[3]) << 16);
            o.z = (u32)f2bf(b[0]) | ((u32)f2bf(b[1]) << 16);
            o.w = (u32)f2bf(b[2]) | ((u32)f2bf(b[3]) << 16);
            int row = L >> 9;
            *(u32x4*)(Xs + (L ^ ((row & 7) << 4))) = o;
        }
    }
    if (tid < 128) ((f32x4*)wts)[tid] = ((const f32x4*)(wt + (size_t)t0 * EE))[tid];
    ((f32x4*)b2s)[tid] = ((const f32x4*)b2)[tid];
    ((f32x4*)b2s)[tid + 256] = ((const f32x4*)b2)[tid + 256];
    __syncthreads();

    f32x4 oacc[4][4];
#pragma unroll
    for (int a = 0; a < 4; ++a)
#pragma unroll
        for (int b = 0; b < 4; ++b) oacc[a][b] = (f32x4)0.0f;

#pragma unroll 1
    for (int e = 0; e < EE; ++e) {
#pragma unroll 1
        for (int ch = 0; ch < 2; ++ch) {
            // ---- GEMM1: wave computes h-rows [wid*64, wid*64+64) of chunk, all 64 tokens
            f32x4 hf[4][4];
#pragma unroll
            for (int a = 0; a < 4; ++a)
#pragma unroll
                for (int b = 0; b < 4; ++b) hf[a][b] = (f32x4)0.0f;

            const u16* w1p = w1t + (((size_t)e * HH) + ch * 256 + wid * 64) * DD;
#pragma unroll
            for (int kb = 0; kb < 8; ++kb) {
                int krow = kb * 32 + lg * 8;
                bf16x8 af[4], bfr[4];
#pragma unroll
                for (int mb = 0; mb < 4; ++mb)
                    af[mb] = ld_frag(w1p + (size_t)(mb * 16 + lr) * DD + krow);
#pragma unroll
                for (int nb = 0; nb < 4; ++nb) {
                    int tok = nb * 16 + lr;
                    int byt = tok * 512 + krow * 2;
                    bfr[nb] = ld_frag(Xs + (byt ^ ((tok & 7) << 4)));
                }
#pragma unroll
                for (int mb = 0; mb < 4; ++mb)
#pragma unroll
                    for (int nb = 0; nb < 4; ++nb)
                        hf[mb][nb] = __builtin_amdgcn_mfma_f32_16x16x32_bf16(af[mb], bfr[nb], hf[mb][nb], 0, 0, 0);
            }
            // epilogue: +b1, gelu (exact), *token weight, pack bf16, write Hs (swizzled)
#pragma unroll
            for (int mb = 0; mb < 4; ++mb) {
                int hl = wid * 64 + mb * 16 + lg * 4;     // h within chunk [0,256)
                f32x4 bb = *(const f32x4*)(b1 + (size_t)e * HH + ch * 256 + hl);
#pragma unroll
                for (int nb = 0; nb < 4; ++nb) {
                    int tok = nb * 16 + lr;
                    float wgt = wts[tok * EE + e];
                    float g[4];
#pragma unroll
                    for (int r = 0; r < 4; ++r) {
                        float v = hf[mb][nb][r] + bb[r];
                        v = 0.5f * v * (1.0f + erff(v * 0.70710678118654752f));
                        g[r] = v * wgt;
                    }
                    u32x2 pk;
                    pk.x = (u32)f2bf(g[0]) | ((u32)f2bf(g[1]) << 16);
                    pk.y = (u32)f2bf(g[2]) | ((u32)f2bf(g[3]) << 16);
                    int byt = tok * 512 + hl * 2;
                    *(u32x2*)(Hs + (byt ^ ((tok & 7) << 4))) = pk;
                }
            }
            __syncthreads();
            // ---- GEMM2: wave computes o-cols [wid*64, wid*64+64), K = this 256-chunk of H
            const u16* w2p = w2t + ((size_t)e * OO + wid * 64) * HH + ch * 256;
#pragma unroll
            for (int kb = 0; kb < 8; ++kb) {
                int krow = kb * 32 + lg * 8;
                bf16x8 af[4], bfr[4];
#pragma unroll
                for (int mb = 0; mb < 4; ++mb) {
                    int tok = mb * 16 + lr;
                    int byt = tok * 512 + krow * 2;
                    af[mb] = ld_frag(Hs + (byt ^ ((tok & 7) << 4)));
                }
#pragma unroll
                for (int nb = 0; nb < 4; ++nb)
                    bfr[nb] = ld_frag(w2p + (size_t)(nb * 16 + lr) * HH + krow);
#pragma unroll
                for (int mb = 0; mb < 4; ++mb)
#pragma unroll
                    for (int nb = 0; nb < 4; ++nb)
                        oacc[mb][nb] = __builtin_amdgcn_mfma_f32_16x16x32_bf16(af[mb], bfr[nb], oacc[mb][nb], 0, 0, 0);
            }
            __syncthreads();
        }
    }

    // epilogue: add sum_e w[t][e]*b2[e][o], store
#pragma unroll
    for (int mb = 0; mb < 4; ++mb) {
#pragma unroll
        for (int r = 0; r < 4; ++r) {
            int trow = mb * 16 + lg * 4 + r;
#pragma unroll
            for (int nb = 0; nb < 4; ++nb) {
                int o = wid * 64 + nb * 16 + lr;
                float wb = 0.f;
#pragma unroll
                for (int e = 0; e < EE; ++e) wb += wts[trow * EE + e] * b2s[e * OO + o];
                out[(size_t)(t0 + trow) * OO + o] = oacc[mb][nb][r] + wb;
            }
        }
    }
}

extern "C" void kernel_launch(void* const* d_in, const int* in_sizes, int n_in,
                              void* d_out, int out_size, void* d_ws, size_t ws_size,
                              hipStream_t stream) {
    const float* x  = (const float*)d_in[0];
    const float* gw = (const float*)d_in[1];
    const float* gb = (const float*)d_in[2];
    const float* w1 = (const float*)d_in[3];
    const float* b1 = (const float*)d_in[4];
    const float* w2 = (const float*)d_in[5];
    const float* b2 = (const float*)d_in[6];
    float* out = (float*)d_out;

    char* ws = (char*)d_ws;
    u16* w1t    = (u16*)(ws);                    // 2 MB
    u16* w2t    = (u16*)(ws + 2097152);          // 2 MB
    float* wt   = (float*)(ws + 4194304);        // 2 MB
    double* prt = (double*)(ws + 6291456);       // 2 KB

    k_conv_w1<<<(EE * HH * DD) / 256, 256, 0, stream>>>(w1, w1t);
    k_conv_w2<<<(EE * OO * HH) / 256, 256, 0, stream>>>(w2, w2t);
    k_gating<<<TT / 256, 256, 0, stream>>>(x, gw, gb, wt, prt);
    k_moe<<<TT / 64, 256, 0, stream>>>(x, w1t, w2t, b1, b2, wt, out);
    k_final<<<1, 256, 0, stream>>>(prt, out + (size_t)TT * OO);
}